// Round 5
// baseline (439.748 us; speedup 1.0000x reference)
//
#include <hip/hip_runtime.h>
#include <hip/hip_bf16.h>
#include <stdint.h>

typedef __attribute__((ext_vector_type(8))) short short8;   // 8 bf16 in 4 VGPRs
typedef __attribute__((ext_vector_type(4))) float floatx4;
typedef unsigned long long ull;

#define AT_LD(p)    __hip_atomic_load((p), __ATOMIC_RELAXED, __HIP_MEMORY_SCOPE_AGENT)
#define AT_ST(p, v) __hip_atomic_store((p), (v), __ATOMIC_RELAXED, __HIP_MEMORY_SCOPE_AGENT)
#define AT_ADD(p, v) __hip_atomic_fetch_add((p), (v), __ATOMIC_RELAXED, __HIP_MEMORY_SCOPE_AGENT)

__device__ __forceinline__ floatx4 mfma_bf16(short8 a, short8 b, floatx4 c) {
  return __builtin_amdgcn_mfma_f32_16x16x32_bf16(a, b, c, 0, 0, 0);
}

// convert 8 contiguous fp32 -> 8 bf16 (one 16B store to LDS)
__device__ __forceinline__ void cvt8_store(const float* __restrict__ src,
                                           __hip_bfloat16* __restrict__ dst) {
  float4 a = *(const float4*)src;
  float4 b = *(const float4*)(src + 4);
  __hip_bfloat16 t[8];
  t[0] = __float2bfloat16(a.x); t[1] = __float2bfloat16(a.y);
  t[2] = __float2bfloat16(a.z); t[3] = __float2bfloat16(a.w);
  t[4] = __float2bfloat16(b.x); t[5] = __float2bfloat16(b.y);
  t[6] = __float2bfloat16(b.z); t[7] = __float2bfloat16(b.w);
  *(uint4*)dst = *(const uint4*)t;
}

// convert 8 contiguous fp32 -> short8 bf16 fragment in registers
__device__ __forceinline__ short8 cvt8_frag(const float* __restrict__ src) {
  float4 a = *(const float4*)src;
  float4 b = *(const float4*)(src + 4);
  union { __hip_bfloat16 h[8]; short8 s; } u;
  u.h[0] = __float2bfloat16(a.x); u.h[1] = __float2bfloat16(a.y);
  u.h[2] = __float2bfloat16(a.z); u.h[3] = __float2bfloat16(a.w);
  u.h[4] = __float2bfloat16(b.x); u.h[5] = __float2bfloat16(b.y);
  u.h[6] = __float2bfloat16(b.z); u.h[7] = __float2bfloat16(b.w);
  return u.s;
}

// =====================================================================
// ONE mega-kernel, grid = 256 = CU count (all co-resident).
// h communication uses TAG-IN-DATA: hseqT is [2048][512] u32 words, each
// word = (bf16 h bits << 16) | (t+1). Producers fire relaxed 8B atomic
// stores and continue (NO waitcnt, NO ordering flag on the chain);
// consumers poll the DATA tags and retry stale chunks. An 8B atomic
// store/load carries tag+data indivisibly -> per-word coherence is free.
// Saves ~1 LLC RTT + a poll + a barrier per recurrence step vs the
// flag-based protocol of rounds 0-4.
// The per-(t,bg) counter remains as a fire-and-forget HINT feeding the
// aggregator's tfront (fc workers also tag-verify their hseq loads, so
// correctness never rests on the hint). xprj keeps the strict
// waitcnt+flag protocol (its consumers don't tag-verify).
// =====================================================================
__global__ __launch_bounds__(256, 1) void fused_all(
    const float* __restrict__ feat,   // [64][512]
    const int*   __restrict__ caps,   // [64][32] int32 or int64
    const float* __restrict__ emb,    // [10000][512]
    const float* __restrict__ Wih,    // [2048][512]
    const float* __restrict__ Whh,    // [2048][512]
    const float* __restrict__ bih,    // [2048]
    const float* __restrict__ bhh,    // [2048]
    const float* __restrict__ fcW,    // [10000][512]
    const float* __restrict__ fcb,    // [10000]
    float* __restrict__ xprj,         // ws: [2048][2048] fp32
    unsigned* __restrict__ hseqT,     // ws: [2048][512] u32 tagged-bf16 (memset 0)
    unsigned* __restrict__ cnt,       // ws: 32 KB zeroed (flags + aux)
    float* __restrict__ out) {        // [64][32][10000] fp32
  __shared__ __align__(16) char sm[16 * 1024 + 16];
  const int tid = threadIdx.x;
  const int w = tid >> 6, l = tid & 63, lr = l & 15, lq = l >> 4;

  unsigned* aux    = cnt + 4096;          // second 16 KB: cold control lines
  unsigned* xcnt   = aux;                 // 16 counters, 128 B apart
  unsigned* xfront = aux + 16 * 32;
  unsigned* tfront = aux + 17 * 32;
  unsigned* queue  = aux + 18 * 32;

  // int64-captions heuristic (tokens <10000 -> high words zero); uniform.
  const bool i64 = (caps[1] == 0) & (caps[3] == 0) & (caps[5] == 0) &
                   (caps[7] == 0) & (caps[9] == 0) & (caps[11] == 0) &
                   (caps[13] == 0);

  if (blockIdx.x < 64) {
    // ---------------- LSTM role (tag-in-data chain) ----------------
    const int bg = blockIdx.x >> 4;   // 0..3  (16 batch rows)
    const int ug = blockIdx.x & 15;   // 0..15 (32 hidden units)
    const int bl = tid >> 5, uu = tid & 31;
    float (*gbuf)[16][32] = (float (*)[16][32])sm;                      // 8 KB
    unsigned short (*hbuf)[32] = (unsigned short (*)[32])(sm + 8192);   // 1 KB bf16 bits
    unsigned* xsh = (unsigned*)(sm + 16384);
    float c0 = 0.f, c1 = 0.f;

    // Whh slice fp32 -> bf16 fragments in regs
    short8 B0[16], B1[16];
    {
      const float* w0 = Whh + (size_t)(w * 512 + ug * 32 + lr) * 512 + lq * 8;
      const float* w1 = w0 + (size_t)16 * 512;
#pragma unroll
      for (int kk = 0; kk < 16; ++kk) {
        B0[kk] = cvt8_frag(w0 + kk * 32);
        B1[kk] = cvt8_frag(w1 + kk * 32);
      }
    }

    unsigned xseen = 0;   // xprj t-pairs known ready (uniform)
    for (int t = 0; t < 32; ++t) {
      // gate on xprj readiness (active only for the first few steps)
      if (xseen * 2 <= (unsigned)t) {
        if (tid == 0) {
          unsigned v;
          while ((v = AT_LD(xfront)) <= (unsigned)(t >> 1))
            __builtin_amdgcn_s_sleep(2);
          *xsh = v;
        }
        __syncthreads();
        xseen = *xsh;
        __syncthreads();
      }
      // prefetch this step's xp (independent of h) — in flight during tag-wait
      const float* xr0 = xprj + ((size_t)t * 64 + bg * 16 + bl) * 2048 + ug * 32 + uu;
      const float* xr1 = xr0 + (size_t)8 * 2048;
      float xi0 = AT_LD(xr0),        xf0 = AT_LD(xr0 + 512);
      float xg0 = AT_LD(xr0 + 1024), xo0 = AT_LD(xr0 + 1536);
      float xi1 = AT_LD(xr1),        xf1 = AT_LD(xr1 + 512);
      float xg1 = AT_LD(xr1 + 1024), xo1 = AT_LD(xr1 + 1536);

      floatx4 a0 = {}, a1 = {};
      if (t > 0) {
        // per-wave tag-verified h load: no flag poll, no block barrier
        const unsigned want = (unsigned)t;   // tag of h_{t-1} is (t-1)+1 = t
        const ull* hp = (const ull*)(hseqT +
                          (size_t)((t - 1) * 64 + bg * 16 + lr) * 512) + lq * 4;
        ull hA[16], hB[16], hC[16], hD[16];
        unsigned okm = 0;
#pragma unroll
        for (int kk = 0; kk < 16; ++kk) {
          hA[kk] = AT_LD(hp + kk * 16 + 0);
          hB[kk] = AT_LD(hp + kk * 16 + 1);
          hC[kk] = AT_LD(hp + kk * 16 + 2);
          hD[kk] = AT_LD(hp + kk * 16 + 3);
        }
#pragma unroll
        for (int kk = 0; kk < 16; ++kk) {
          bool ok = ((((unsigned)hA[kk] ^ want) | ((unsigned)hB[kk] ^ want) |
                      ((unsigned)hC[kk] ^ want) | ((unsigned)hD[kk] ^ want)) &
                     0xFFFFu) == 0u;
          okm |= (unsigned)__all(ok) << kk;
        }
        while (okm != 0xFFFFu) {
          __builtin_amdgcn_s_sleep(1);
#pragma unroll
          for (int kk = 0; kk < 16; ++kk) {
            if (!(okm & (1u << kk))) {
              hA[kk] = AT_LD(hp + kk * 16 + 0);
              hB[kk] = AT_LD(hp + kk * 16 + 1);
              hC[kk] = AT_LD(hp + kk * 16 + 2);
              hD[kk] = AT_LD(hp + kk * 16 + 3);
              bool ok = ((((unsigned)hA[kk] ^ want) | ((unsigned)hB[kk] ^ want) |
                          ((unsigned)hC[kk] ^ want) | ((unsigned)hD[kk] ^ want)) &
                         0xFFFFu) == 0u;
              okm |= (unsigned)__all(ok) << kk;
            }
          }
        }
#pragma unroll
        for (int kk = 0; kk < 16; ++kk) {
          union { unsigned short s[8]; short8 v; } fr;
          fr.s[0] = (unsigned short)(hA[kk] >> 16);
          fr.s[1] = (unsigned short)(hA[kk] >> 48);
          fr.s[2] = (unsigned short)(hB[kk] >> 16);
          fr.s[3] = (unsigned short)(hB[kk] >> 48);
          fr.s[4] = (unsigned short)(hC[kk] >> 16);
          fr.s[5] = (unsigned short)(hC[kk] >> 48);
          fr.s[6] = (unsigned short)(hD[kk] >> 16);
          fr.s[7] = (unsigned short)(hD[kk] >> 48);
          a0 = mfma_bf16(fr.v, B0[kk], a0);
          a1 = mfma_bf16(fr.v, B1[kk], a1);
        }
      }
#pragma unroll
      for (int r = 0; r < 4; ++r) {
        gbuf[w][lq * 4 + r][lr] = a0[r];
        gbuf[w][lq * 4 + r][16 + lr] = a1[r];
      }
      __syncthreads();
      {
        float gi = gbuf[0][bl][uu] + xi0, gf = gbuf[1][bl][uu] + xf0;
        float gg = gbuf[2][bl][uu] + xg0, go = gbuf[3][bl][uu] + xo0;
        float c = 1.f / (1.f + __expf(-gf)) * c0 + 1.f / (1.f + __expf(-gi)) * tanhf(gg);
        c0 = c;
        __hip_bfloat16 hb = __float2bfloat16(1.f / (1.f + __expf(-go)) * tanhf(c));
        hbuf[bl][uu] = *(const unsigned short*)&hb;
      }
      {
        float gi = gbuf[0][bl + 8][uu] + xi1, gf = gbuf[1][bl + 8][uu] + xf1;
        float gg = gbuf[2][bl + 8][uu] + xg1, go = gbuf[3][bl + 8][uu] + xo1;
        float c = 1.f / (1.f + __expf(-gf)) * c1 + 1.f / (1.f + __expf(-gi)) * tanhf(gg);
        c1 = c;
        __hip_bfloat16 hb = __float2bfloat16(1.f / (1.f + __expf(-go)) * tanhf(c));
        hbuf[bl + 8][uu] = *(const unsigned short*)&hb;
      }
      __syncthreads();
      {
        // fire-and-forget tagged store: 256 threads x 1 ull (2 tagged words)
        const unsigned tagOut = (unsigned)(t + 1);
        int r = tid >> 4, p = tid & 15;
        unsigned lo = ((unsigned)hbuf[r][2 * p]     << 16) | tagOut;
        unsigned hi = ((unsigned)hbuf[r][2 * p + 1] << 16) | tagOut;
        ull val = ((ull)hi << 32) | (ull)lo;
        AT_ST((ull*)(hseqT + (size_t)(t * 64 + bg * 16 + r) * 512 + ug * 32) + p, val);
      }
      if (tid == 0) AT_ADD(cnt + (t * 4 + bg) * 32, 1u);   // HINT only (no waitcnt)
      // no trailing barrier: next hbuf write is after the next gbuf barrier
    }
  } else if (blockIdx.x == 64) {
    // ---------------- aggregator: sole poller of hot counter lines ----------------
    if (tid == 0) {
      for (int ib = 0; ib < 16; ++ib) {
        while (AT_LD(xcnt + ib * 32) < 16u) __builtin_amdgcn_s_sleep(2);
        AT_ST(xfront, (unsigned)(ib + 1));
      }
      for (int t = 0; t < 32; ++t) {
        for (int bg = 0; bg < 4; ++bg) {
          const unsigned* f = cnt + (t * 4 + bg) * 32;
          while (AT_LD(f) < 16u) __builtin_amdgcn_s_sleep(8);
        }
        AT_ST(tfront, (unsigned)(t + 1));
      }
    }
    // other threads fall through and park at the pool's first barrier
  }

  // ---------------- worker pool (all 256 blocks end up here) ----------------
  __hip_bfloat16* As = (__hip_bfloat16*)sm;           // 8 KB
  __hip_bfloat16* Bs = As + 128 * 32;                 // 8 KB
  int* nslot = (int*)(sm + 16384);
  const int wr = (w & 1) * 64, wc = (w >> 1) * 64;
  // per-it staging geometry (fixed per thread)
  const int flatA0 = 0 * 256 + w * 64 + l, flatA1 = 1 * 256 + w * 64 + l;
  const int row0 = flatA0 >> 2, c80 = (flatA0 & 3) * 8;
  const int row1 = flatA1 >> 2, c81 = (flatA1 & 3) * 8;

  for (;;) {
    __syncthreads();   // LDS handoff (role->pool and between tiles)
    if (tid == 0) *nslot = (int)AT_ADD(queue, 1u);
    __syncthreads();
    const int n = *nslot;
    if (n >= 256 + 16 * 79) break;

    if (n < 256) {
      // ============ xprj tile: xprj[ib*128.., jb*128..] = Xs * Wih^T + b ============
      const int ib = n >> 4, jb = n & 15;   // ib ascending == t ascending
      const float* sA[2];
      const float* sB[2];
      {
        const int rg0 = ib * 128 + row0, tt0 = rg0 >> 6, b0 = rg0 & 63;
        const int rg1 = ib * 128 + row1, tt1 = rg1 >> 6, b1v = rg1 & 63;
        if (tt0 == 0) sA[0] = feat + (size_t)b0 * 512 + c80;
        else {
          int idx = i64 ? caps[(size_t)(b0 * 32 + tt0) * 2] : caps[b0 * 32 + tt0];
          idx = idx < 0 ? 0 : (idx > 9999 ? 9999 : idx);
          sA[0] = emb + (size_t)idx * 512 + c80;
        }
        if (tt1 == 0) sA[1] = feat + (size_t)b1v * 512 + c81;
        else {
          int idx = i64 ? caps[(size_t)(b1v * 32 + tt1) * 2] : caps[b1v * 32 + tt1];
          idx = idx < 0 ? 0 : (idx > 9999 ? 9999 : idx);
          sA[1] = emb + (size_t)idx * 512 + c81;
        }
        sB[0] = Wih + (size_t)(jb * 128 + row0) * 512 + c80;
        sB[1] = Wih + (size_t)(jb * 128 + row1) * 512 + c81;
      }
      floatx4 acc[4][4] = {};
      for (int kt = 0; kt < 16; ++kt) {
        const int k0 = kt * 32;
        cvt8_store(sA[0] + k0, As + (size_t)flatA0 * 8);
        cvt8_store(sB[0] + k0, Bs + (size_t)flatA0 * 8);
        cvt8_store(sA[1] + k0, As + (size_t)flatA1 * 8);
        cvt8_store(sB[1] + k0, Bs + (size_t)flatA1 * 8);
        __syncthreads();
        short8 af[4], bfr[4];
#pragma unroll
        for (int mt = 0; mt < 4; ++mt)
          af[mt] = *(const short8*)(As + (wr + mt * 16 + lr) * 32 + lq * 8);
#pragma unroll
        for (int nt = 0; nt < 4; ++nt)
          bfr[nt] = *(const short8*)(Bs + (wc + nt * 16 + lr) * 32 + lq * 8);
#pragma unroll
        for (int mt = 0; mt < 4; ++mt)
#pragma unroll
          for (int nt = 0; nt < 4; ++nt)
            acc[mt][nt] = mfma_bf16(af[mt], bfr[nt], acc[mt][nt]);
        __syncthreads();
      }
      // epilogue: agent-scope atomic stores (consumed by lstm blocks this kernel)
#pragma unroll
      for (int mt = 0; mt < 4; ++mt) {
#pragma unroll
        for (int nt = 0; nt < 4; ++nt) {
          int col = jb * 128 + wc + nt * 16 + lr;
          float bias = bih[col] + bhh[col];
#pragma unroll
          for (int r = 0; r < 4; ++r) {
            int row = ib * 128 + wr + mt * 16 + lq * 4 + r;
            AT_ST(xprj + (size_t)row * 2048 + col, acc[mt][nt][r] + bias);
          }
        }
      }
      __builtin_amdgcn_s_waitcnt(0);   // strict: xprj consumers don't tag-verify
      __syncthreads();
      if (tid == 0) AT_ADD(xcnt + ib * 32, 1u);
    } else {
      // ============ fc tile: out = hseq * fcW^T + fcb ============
      const int m = n - 256;
      const int ib = m / 79, jb = m - ib * 79;   // ib ascending == t ascending
      if (tid == 0) {
        const unsigned need = (unsigned)(2 * ib + 2);   // hint gate
        while (AT_LD(tfront) < need) __builtin_amdgcn_s_sleep(16);
      }
      __syncthreads();
      int rb0 = jb * 128 + row0; if (rb0 > 9999) rb0 = 9999;
      int rb1 = jb * 128 + row1; if (rb1 > 9999) rb1 = 9999;
      const float* sB0 = fcW + (size_t)rb0 * 512 + c80;
      const float* sB1 = fcW + (size_t)rb1 * 512 + c81;
      const ull* pA0 = (const ull*)(hseqT + (size_t)(ib * 128 + row0) * 512 + c80);
      const ull* pA1 = (const ull*)(hseqT + (size_t)(ib * 128 + row1) * 512 + c81);
      const unsigned w0t = (unsigned)((ib * 128 + row0) >> 6) + 1;   // tag = t+1
      const unsigned w1t = (unsigned)((ib * 128 + row1) >> 6) + 1;
      floatx4 acc[4][4] = {};
      for (int kt = 0; kt < 16; ++kt) {
        const int o = kt * 16;
        // A: tag-verified LLC loads (correctness even if tfront hint runs ahead)
        ull q0 = AT_LD(pA0 + o + 0), q1 = AT_LD(pA0 + o + 1);
        ull q2 = AT_LD(pA0 + o + 2), q3 = AT_LD(pA0 + o + 3);
        ull r0 = AT_LD(pA1 + o + 0), r1 = AT_LD(pA1 + o + 1);
        ull r2 = AT_LD(pA1 + o + 2), r3 = AT_LD(pA1 + o + 3);
        // B staged while A in flight
        cvt8_store(sB0 + kt * 32, Bs + (size_t)flatA0 * 8);
        cvt8_store(sB1 + kt * 32, Bs + (size_t)flatA1 * 8);
        while (((((unsigned)q0 ^ w0t) | ((unsigned)q1 ^ w0t) |
                 ((unsigned)q2 ^ w0t) | ((unsigned)q3 ^ w0t) |
                 ((unsigned)r0 ^ w1t) | ((unsigned)r1 ^ w1t) |
                 ((unsigned)r2 ^ w1t) | ((unsigned)r3 ^ w1t)) & 0xFFFFu) != 0u) {
          __builtin_amdgcn_s_sleep(2);
          q0 = AT_LD(pA0 + o + 0); q1 = AT_LD(pA0 + o + 1);
          q2 = AT_LD(pA0 + o + 2); q3 = AT_LD(pA0 + o + 3);
          r0 = AT_LD(pA1 + o + 0); r1 = AT_LD(pA1 + o + 1);
          r2 = AT_LD(pA1 + o + 2); r3 = AT_LD(pA1 + o + 3);
        }
        {
          union { unsigned short s[8]; uint4 u; } fa;
          fa.s[0] = (unsigned short)(q0 >> 16); fa.s[1] = (unsigned short)(q0 >> 48);
          fa.s[2] = (unsigned short)(q1 >> 16); fa.s[3] = (unsigned short)(q1 >> 48);
          fa.s[4] = (unsigned short)(q2 >> 16); fa.s[5] = (unsigned short)(q2 >> 48);
          fa.s[6] = (unsigned short)(q3 >> 16); fa.s[7] = (unsigned short)(q3 >> 48);
          *(uint4*)(As + (size_t)flatA0 * 8) = fa.u;
          fa.s[0] = (unsigned short)(r0 >> 16); fa.s[1] = (unsigned short)(r0 >> 48);
          fa.s[2] = (unsigned short)(r1 >> 16); fa.s[3] = (unsigned short)(r1 >> 48);
          fa.s[4] = (unsigned short)(r2 >> 16); fa.s[5] = (unsigned short)(r2 >> 48);
          fa.s[6] = (unsigned short)(r3 >> 16); fa.s[7] = (unsigned short)(r3 >> 48);
          *(uint4*)(As + (size_t)flatA1 * 8) = fa.u;
        }
        __syncthreads();
        short8 af[4], bfr[4];
#pragma unroll
        for (int mt = 0; mt < 4; ++mt)
          af[mt] = *(const short8*)(As + (wr + mt * 16 + lr) * 32 + lq * 8);
#pragma unroll
        for (int nt = 0; nt < 4; ++nt)
          bfr[nt] = *(const short8*)(Bs + (wc + nt * 16 + lr) * 32 + lq * 8);
#pragma unroll
        for (int mt = 0; mt < 4; ++mt)
#pragma unroll
          for (int nt = 0; nt < 4; ++nt)
            acc[mt][nt] = mfma_bf16(af[mt], bfr[nt], acc[mt][nt]);
        __syncthreads();
      }
#pragma unroll
      for (int mt = 0; mt < 4; ++mt) {
#pragma unroll
        for (int nt = 0; nt < 4; ++nt) {
          int col = jb * 128 + wc + nt * 16 + lr;
          if (col < 10000) {
            float bias = fcb[col];
#pragma unroll
            for (int r = 0; r < 4; ++r) {
              int row = ib * 128 + wr + mt * 16 + lq * 4 + r;
              size_t orow = (size_t)((row & 63) * 32 + (row >> 6));   // [B,T,V]
              out[orow * 10000 + col] = acc[mt][nt][r] + bias;
            }
          }
        }
      }
    }
  }
}

extern "C" void kernel_launch(void* const* d_in, const int* in_sizes, int n_in,
                              void* d_out, int out_size, void* d_ws, size_t ws_size,
                              hipStream_t stream) {
  const float* feat = (const float*)d_in[0];
  const int* caps   = (const int*)d_in[1];
  const float* emb  = (const float*)d_in[2];
  const float* Wih  = (const float*)d_in[3];
  const float* Whh  = (const float*)d_in[4];
  const float* bih  = (const float*)d_in[5];
  const float* bhh  = (const float*)d_in[6];
  const float* fcW  = (const float*)d_in[7];
  const float* fcb  = (const float*)d_in[8];
  float* out = (float*)d_out;                  // [64,32,10000] fp32

  const size_t MB = 1048576;
  char* ws = (char*)d_ws;
  float*    xprj  = (float*)(ws);                    // 16 MB [2048,2048]
  unsigned* hseqT = (unsigned*)(ws + 16 * MB);       // 4 MB  [2048,512] tagged bf16
  unsigned* cnt   = (unsigned*)(ws + 20 * MB);       // 32 KB flags + aux

  // zero hseqT (stale-tag guard; also protects re-poisoned graph replays) + flags
  hipMemsetAsync(ws + 16 * MB, 0, 4 * MB + 32768, stream);

  fused_all<<<256, 256, 0, stream>>>(feat, caps, emb, Wih, Whh, bih, bhh,
                                     fcW, fcb, xprj, hseqT, cnt, out);
}